// Round 4
// baseline (3921.469 us; speedup 1.0000x reference)
//
#include <hip/hip_runtime.h>
#include <math.h>
#include <float.h>

#define NB     64      // batch
#define S_EN   50
#define S_DE   50
#define EMB_E  64
#define EMB_D  32
#define HID    32
#define G4     128     // 4*H
#define DE_VSZ 19000
#define OUT_B  (S_DE * DE_VSZ)

#define NG     4       // batch groups
#define JB     16      // batches per group (NG*JB = 64)
#define NSL    30      // vocab slices
#define NRS    640     // rows per slice (30*640 = 19200 >= 19000)
#define NBLK   (NG * NSL)   // 120 blocks <= 256 CUs -> co-residency by capacity
#define NTHR   640     // 10 waves; fc: one row per thread
#define WST    100     // LDS weight row stride in floats (400B, 16B-aligned)
#define KVSTR  64      // kv slice-stride per (g,jb) row (30 used, 64 for lines)
#define POLL_CAP 200000 // bounded poll: deadlock -> terminating wrong answer

typedef unsigned long long ull;

__device__ __forceinline__ float sigmoidf_(float x) { return 1.0f / (1.0f + expf(-x)); }

// monotone float->uint: a<b <=> ordf(a)<ordf(b)
__device__ __forceinline__ unsigned ordf_(float f) {
    unsigned u = __float_as_uint(f);
    return (u & 0x80000000u) ? ~u : (u | 0x80000000u);
}

// Grid: 120 blocks = 4 batch-groups x 30 vocab slices. Block (g, isl):
//  - redundantly runs the LSTM for its group's 16 batches (bitwise identical
//    across the 30 slice-siblings),
//  - thread owns ONE fc row (r = isl*640+tid) in VGPRs and computes its logit
//    for ALL 16 batches -> out stores are 64 consecutive dwords per wave
//    store instruction (fixes round-3's 35x per-lane write amplification),
//  - publishes 16 packed keys [tag:6|ordf:32|~idx:15] (relaxed agent atomics).
// TWO-HOP rendezvous: leader block (isl==0) of each group polls the 30x16
// keys, reduces argmax, publishes 16 token words [tag|token]; siblings poll
// ONE 128-B line. Every cross-block link is a single-word tagged value -> no
// fences. Chain-gating -> no ABA, no parity buffers.
__global__ __launch_bounds__(NTHR, 2) void seq2seq_cstore(
    const int*   __restrict__ en_batch, const int* __restrict__ en_lens,
    const int*   __restrict__ de_batch,
    const float* __restrict__ en_emb,
    const float* __restrict__ eWih, const float* __restrict__ eWhh,
    const float* __restrict__ ebih, const float* __restrict__ ebhh,
    const float* __restrict__ de_emb,
    const float* __restrict__ dWih, const float* __restrict__ dWhh,
    const float* __restrict__ dbih, const float* __restrict__ dbhh,
    const float* __restrict__ fcW,  const float* __restrict__ fcb,
    float*       __restrict__ out,
    ull* kv,   // (NG, JB, KVSTR) packed slice keys
    ull* tk)   // (NG, JB) leader-reduced token words [tag:32|token:32]
{
    const int tid  = threadIdx.x;
    const int lane = tid & 63;
    const int wvi  = tid >> 6;           // wave 0..9
    const int bx   = blockIdx.x;
    const int g    = bx & 3;             // batch group
    const int isl  = bx >> 2;            // vocab slice 0..29

    __shared__ __align__(16) float s_w[G4 * WST];   // 51.2 KB enc/dec weights
    __shared__ __align__(16) float s_xh[JB][104];   // x|h per batch (enc: h@64, dec: h@32)
    __shared__ ull  s_red[10 * JB];                 // per-wave per-batch keys
    __shared__ int  s_tok[JB];
    __shared__ int  s_len[JB];

    // ---- zero out[:, 0, :] (wave-contiguous float4) ----
    for (int idx = bx * NTHR + tid; idx < NB * (DE_VSZ / 4); idx += NBLK * NTHR) {
        const int bb = idx / (DE_VSZ / 4);
        const int qq = idx - bb * (DE_VSZ / 4);
        *(float4*)(out + (size_t)bb * OUT_B + (size_t)qq * 4) = make_float4(0.f, 0.f, 0.f, 0.f);
    }

    // ---- stage encoder weights: row r = eWih[r][0..63] | eWhh[r][0..31] ----
    for (int idx = tid; idx < G4 * 96; idx += NTHR) {
        const int row = idx / 96, k = idx - row * 96;
        s_w[row * WST + k] = (k < EMB_E) ? eWih[row * EMB_E + k]
                                         : eWhh[row * HID + (k - EMB_E)];
    }
    if (tid < JB) {
        s_len[tid] = en_lens[g * JB + tid];
        s_tok[tid] = de_batch[(g * JB + tid) * S_DE + 0];
    }

    // LSTM thread mapping: (jb = tid>>5, u = tid&31) for tid < 512.
    const int jb = tid >> 5;
    const int u  = tid & 31;
    float ebs0=0,ebs1=0,ebs2=0,ebs3=0, dbs0=0,dbs1=0,dbs2=0,dbs3=0;
    float creg = 0.f;
    if (tid < JB * HID) {
        ebs0 = ebih[u]      + ebhh[u];
        ebs1 = ebih[32 + u] + ebhh[32 + u];
        ebs2 = ebih[64 + u] + ebhh[64 + u];
        ebs3 = ebih[96 + u] + ebhh[96 + u];
        dbs0 = dbih[u]      + dbhh[u];
        dbs1 = dbih[32 + u] + dbhh[32 + u];
        dbs2 = dbih[64 + u] + dbhh[64 + u];
        dbs3 = dbih[96 + u] + dbhh[96 + u];
        s_xh[jb][64 + u] = 0.f;          // encoder h init
    }

    // ---- fc: ONE row per thread; weights live in VGPRs ----
    const int  r      = isl * NRS + tid;          // consecutive lanes = consecutive rows
    const bool rvalid = (r < DE_VSZ);
    float fw[32]; float fb = 0.f;
    {
        const float4* w4p = (const float4*)&fcW[(size_t)(rvalid ? r : 0) * HID];
        #pragma unroll
        for (int c = 0; c < 8; ++c) {
            const float4 v = w4p[c];
            fw[c*4+0] = v.x; fw[c*4+1] = v.y; fw[c*4+2] = v.z; fw[c*4+3] = v.w;
        }
        if (rvalid) fb = fcb[r];
    }
    __syncthreads();

    int maxlen = 1;
    for (int j = 0; j < JB; ++j) maxlen = max(maxlen, s_len[j]);
    const int mylen = (tid < JB * HID) ? s_len[jb] : 0;

    // ---- encoder: 16 batches, mask t < len[jb] (matches jnp.where(valid)) ----
    for (int t = 0; t < maxlen; ++t) {
        if (tid < JB * 16) {
            const int jj = tid >> 4, q = tid & 15;
            const int etok = en_batch[(g * JB + jj) * S_EN + t];
            *(float4*)&s_xh[jj][q * 4] = *(const float4*)&en_emb[(size_t)etok * EMB_E + q * 4];
        }
        __syncthreads();
        float cnew = 0.f, hnew = 0.f;
        if (tid < JB * HID) {
            float a0 = ebs0, a1 = ebs1, a2 = ebs2, a3 = ebs3;
            #pragma unroll
            for (int kc = 0; kc < 24; ++kc) {
                const float4 xh = *(const float4*)&s_xh[jb][kc * 4];
                const float4 w0 = *(const float4*)&s_w[(u     ) * WST + kc * 4];
                const float4 w1 = *(const float4*)&s_w[(u + 32) * WST + kc * 4];
                const float4 w2 = *(const float4*)&s_w[(u + 64) * WST + kc * 4];
                const float4 w3 = *(const float4*)&s_w[(u + 96) * WST + kc * 4];
                a0 = fmaf(xh.x,w0.x,a0); a0 = fmaf(xh.y,w0.y,a0); a0 = fmaf(xh.z,w0.z,a0); a0 = fmaf(xh.w,w0.w,a0);
                a1 = fmaf(xh.x,w1.x,a1); a1 = fmaf(xh.y,w1.y,a1); a1 = fmaf(xh.z,w1.z,a1); a1 = fmaf(xh.w,w1.w,a1);
                a2 = fmaf(xh.x,w2.x,a2); a2 = fmaf(xh.y,w2.y,a2); a2 = fmaf(xh.z,w2.z,a2); a2 = fmaf(xh.w,w2.w,a2);
                a3 = fmaf(xh.x,w3.x,a3); a3 = fmaf(xh.y,w3.y,a3); a3 = fmaf(xh.z,w3.z,a3); a3 = fmaf(xh.w,w3.w,a3);
            }
            const float ii = sigmoidf_(a0), ff = sigmoidf_(a1);
            const float gg = tanhf(a2),     oo = sigmoidf_(a3);
            cnew = ff * creg + ii * gg;
            hnew = oo * tanhf(cnew);
        }
        __syncthreads();
        if (tid < JB * HID && t < mylen) {
            creg = cnew;
            s_xh[jb][64 + u] = hnew;
        }
        __syncthreads();
    }

    // ---- handoff: h -> decoder slot [32+u]; restage decoder weights ----
    float hcur = 0.f;
    if (tid < JB * HID) hcur = s_xh[jb][64 + u];   // read [64..95]
    for (int idx = tid; idx < G4 * 64; idx += NTHR) {
        const int row = idx >> 6, k = idx & 63;
        s_w[row * WST + k] = (k < HID) ? dWih[row * HID + k]
                                       : dWhh[row * HID + (k - HID)];
    }
    if (tid < JB * HID) s_xh[jb][32 + u] = hcur;   // write [32..63] (disjoint)
    __syncthreads();

    // ---- decoder: 49 steps ----
    for (int s = 1; s < S_DE; ++s) {
        // (a) x = de_emb[tok]
        if (tid < JB * 8) {
            const int jj = tid >> 3, q = tid & 7;
            const int tk_ = s_tok[jj];
            *(float4*)&s_xh[jj][q * 4] = *(const float4*)&de_emb[(size_t)tk_ * EMB_D + q * 4];
        }
        __syncthreads();

        // (b) gates fully in regs (thread owns (jb,u): 4 gates + cell state)
        float hnew = 0.f;
        if (tid < JB * HID) {
            float a0 = dbs0, a1 = dbs1, a2 = dbs2, a3 = dbs3;
            #pragma unroll
            for (int kc = 0; kc < 16; ++kc) {
                const float4 xh = *(const float4*)&s_xh[jb][kc * 4];
                const float4 w0 = *(const float4*)&s_w[(u     ) * WST + kc * 4];
                const float4 w1 = *(const float4*)&s_w[(u + 32) * WST + kc * 4];
                const float4 w2 = *(const float4*)&s_w[(u + 64) * WST + kc * 4];
                const float4 w3 = *(const float4*)&s_w[(u + 96) * WST + kc * 4];
                a0 = fmaf(xh.x,w0.x,a0); a0 = fmaf(xh.y,w0.y,a0); a0 = fmaf(xh.z,w0.z,a0); a0 = fmaf(xh.w,w0.w,a0);
                a1 = fmaf(xh.x,w1.x,a1); a1 = fmaf(xh.y,w1.y,a1); a1 = fmaf(xh.z,w1.z,a1); a1 = fmaf(xh.w,w1.w,a1);
                a2 = fmaf(xh.x,w2.x,a2); a2 = fmaf(xh.y,w2.y,a2); a2 = fmaf(xh.z,w2.z,a2); a2 = fmaf(xh.w,w2.w,a2);
                a3 = fmaf(xh.x,w3.x,a3); a3 = fmaf(xh.y,w3.y,a3); a3 = fmaf(xh.z,w3.z,a3); a3 = fmaf(xh.w,w3.w,a3);
            }
            const float ii = sigmoidf_(a0), ff = sigmoidf_(a1);
            const float gg = tanhf(a2),     oo = sigmoidf_(a3);
            creg = ff * creg + ii * gg;
            hnew = oo * tanhf(creg);
        }
        __syncthreads();
        if (tid < JB * HID) s_xh[jb][32 + u] = hnew;
        __syncthreads();

        // (c) fc: thread's row x ALL 16 batches; h broadcast from LDS (uniform
        //     addr -> conflict-free); stores are 64-consecutive-dword per wave.
        float acc[JB];
        #pragma unroll
        for (int j = 0; j < JB; ++j) {
            const float* hj = &s_xh[j][32];
            float a = fb;
            #pragma unroll
            for (int kc = 0; kc < 8; ++kc) {
                const float4 h4 = *(const float4*)&hj[kc * 4];
                a = fmaf(fw[kc*4+0], h4.x, a);
                a = fmaf(fw[kc*4+1], h4.y, a);
                a = fmaf(fw[kc*4+2], h4.z, a);
                a = fmaf(fw[kc*4+3], h4.w, a);
            }
            acc[j] = a;
        }
        {
            float* od = out + (size_t)(g * JB) * OUT_B + (size_t)s * DE_VSZ + r;
            #pragma unroll
            for (int j = 0; j < JB; ++j)
                if (rvalid) od[(size_t)j * OUT_B] = acc[j];
        }
        if (s == S_DE - 1) break;   // final step: no one consumes these keys

        // per-batch argmax keys: full 64-lane xor reduce, then cross-wave
        #pragma unroll
        for (int j = 0; j < JB; ++j) {
            ull kj = rvalid ? (((ull)ordf_(acc[j]) << 15) | (unsigned)((~r) & 0x7FFF)) : 0ull;
            #pragma unroll
            for (int off = 1; off < 64; off <<= 1) {
                const ull ok = __shfl_xor(kj, off);
                if (ok > kj) kj = ok;
            }
            if (lane == 0) s_red[wvi * JB + j] = kj;
        }
        __syncthreads();

        if (tid < JB) {            // final reduce over 10 waves; publish tagged key
            ull m = s_red[tid];
            for (int w = 1; w < 10; ++w) {
                const ull k2 = s_red[w * JB + tid];
                if (k2 > m) m = k2;
            }
            // tag:6 @47 | ordf:32 @15 | ~idx:15 ; batch index == tid
            __hip_atomic_store(&kv[((size_t)g * JB + tid) * KVSTR + isl],
                               ((ull)s << 47) | m,
                               __ATOMIC_RELAXED, __HIP_MEMORY_SCOPE_AGENT);
        }

        if (isl == 0) {
            // ---- leader: poll all 30x16 keys, reduce, publish tokens
            ull k0 = 0;
            int iter = 0;
            const size_t kbase = ((size_t)g * JB + jb) * KVSTR;   // jb = tid>>5
            for (;;) {
                int ok = 1;
                if (tid < JB * HID && u < NSL) {
                    k0 = __hip_atomic_load(&kv[kbase + u], __ATOMIC_RELAXED, __HIP_MEMORY_SCOPE_AGENT);
                    ok = ((int)(k0 >> 47) == s);
                }
                if (__syncthreads_and(ok)) break;
                if (++iter > POLL_CAP) break;   // safety: never hang the queue
                __builtin_amdgcn_s_sleep(2);
            }
            if (tid < JB * HID) {
                ull m = (u < NSL) ? k0 : 0ull;
                #pragma unroll
                for (int off = 1; off < 32; off <<= 1) {   // u-groups are 32-lane halves
                    const ull ok2 = __shfl_xor(m, off);
                    if (ok2 > m) m = ok2;
                }
                if (u == 0) {
                    const int token = (int)((~(unsigned)m) & 0x7FFF);
                    s_tok[jb] = token;
                    __hip_atomic_store(&tk[g * JB + jb],
                                       ((ull)s << 32) | (unsigned)token,
                                       __ATOMIC_RELAXED, __HIP_MEMORY_SCOPE_AGENT);
                }
            }
            __syncthreads();
        } else {
            // ---- sibling: poll ONE 128-B line (16 token words) with wave 0
            ull tw = 0;
            int iter = 0;
            for (;;) {
                int ok = 1;
                if (wvi == 0 && lane < JB) {
                    tw = __hip_atomic_load(&tk[g * JB + lane], __ATOMIC_RELAXED, __HIP_MEMORY_SCOPE_AGENT);
                    ok = ((int)(tw >> 32) == s);
                }
                if (__syncthreads_and(ok)) break;
                if (++iter > POLL_CAP) break;   // safety: never hang the queue
                __builtin_amdgcn_s_sleep(2);
            }
            if (wvi == 0 && lane < JB) s_tok[lane] = (int)(tw & 0x7FFF);
            __syncthreads();
        }
    }
}

extern "C" void kernel_launch(void* const* d_in, const int* in_sizes, int n_in,
                              void* d_out, int out_size, void* d_ws, size_t ws_size,
                              hipStream_t stream) {
    (void)in_sizes; (void)n_in; (void)out_size; (void)ws_size;
    const int*   en_batch = (const int*)  d_in[0];
    const int*   en_lens  = (const int*)  d_in[1];
    const int*   de_batch = (const int*)  d_in[2];
    const float* en_emb   = (const float*)d_in[3];
    const float* eWih     = (const float*)d_in[4];
    const float* eWhh     = (const float*)d_in[5];
    const float* ebih     = (const float*)d_in[6];
    const float* ebhh     = (const float*)d_in[7];
    const float* de_emb   = (const float*)d_in[8];
    const float* dWih     = (const float*)d_in[9];
    const float* dWhh     = (const float*)d_in[10];
    const float* dbih     = (const float*)d_in[11];
    const float* dbhh     = (const float*)d_in[12];
    const float* fcW      = (const float*)d_in[13];
    const float* fcb      = (const float*)d_in[14];
    float* out = (float*)d_out;

    ull* kv = (ull*)d_ws;                           // 4*16*64*8 = 32 KB
    ull* tk = (ull*)((char*)d_ws + 32768);          // 4*16*8   = 512 B
    hipMemsetAsync(d_ws, 0, 40960, stream);         // tag 0 != any step s>=1

    seq2seq_cstore<<<NBLK, NTHR, 0, stream>>>(
        en_batch, en_lens, de_batch, en_emb, eWih, eWhh, ebih, ebhh,
        de_emb, dWih, dWhh, dbih, dbhh, fcW, fcb, out, kv, tk);
}

// Round 5
// 1501.646 us; speedup vs baseline: 2.6114x; 2.6114x over previous
//
#include <hip/hip_runtime.h>
#include <math.h>
#include <float.h>

#define NB     64      // batch
#define S_EN   50
#define S_DE   50
#define EMB_E  64
#define EMB_D  32
#define HID    32
#define G4     128     // 4*H
#define DE_VSZ 19000
#define OUT_B  (S_DE * DE_VSZ)

#define NSLB   4       // vocab slices per batch
#define SLR    4750    // rows per slice (4*4750 = 19000 exactly)
#define NBLK   (NB * NSLB)  // 256 blocks = CU count -> co-residency by capacity
#define NTHR   512     // 8 waves
#define NRPT   10      // fc rows per thread (ceil 4750/512)
#define WST    97      // LDS weight row stride: (97*t+k)%32=(t+k)%32 -> conflict-free
#define KXS    16      // kv u64-stride per batch (128 B: one line per batch)
#define POLL_CAP 200000 // bounded poll: failure -> terminating wrong answer

typedef unsigned long long ull;

__device__ __forceinline__ float sigmoidf_(float x) { return 1.0f / (1.0f + expf(-x)); }

// monotone float->uint: a<b <=> ordf(a)<ordf(b)
__device__ __forceinline__ unsigned ordf_(float f) {
    unsigned u = __float_as_uint(f);
    return (u & 0x80000000u) ? ~u : (u | 0x80000000u);
}

// Grid: 256 blocks = 64 batches x 4 vocab slices. Batches are fully
// INDEPENDENT (no global lockstep): block (b,q) redundantly runs batch b's
// encoder+decoder LSTM (bitwise identical across the 4 siblings) and owns fc
// rows [q*4750, (q+1)*4750), streamed from L2 each step (fcW = 2.43 MB,
// XCD-L2-resident).
// Rendezvous = minimal 4-way exchange per batch per step, via atomic RMWs
// ONLY: publish with atomic_exchange, poll with atomic_fetch_add(0). RMWs
// execute at the device coherence point, so visibility does not depend on
// L2 eviction timing (the round-2..4 ~78us/step constant) or on compiler
// cache-bit choices for relaxed atomic load/store. Keys are tagged
// [step:6|ordf:32|~idx:15]; parity-2 buffering (sibling skew provably <=1
// step). No fences anywhere. POLL_CAP keeps any failure terminating.
__global__ __launch_bounds__(NTHR, 2) void seq2seq_rmw4(
    const int*   __restrict__ en_batch, const int* __restrict__ en_lens,
    const int*   __restrict__ de_batch,
    const float* __restrict__ en_emb,
    const float* __restrict__ eWih, const float* __restrict__ eWhh,
    const float* __restrict__ ebih, const float* __restrict__ ebhh,
    const float* __restrict__ de_emb,
    const float* __restrict__ dWih, const float* __restrict__ dWhh,
    const float* __restrict__ dbih, const float* __restrict__ dbhh,
    const float* __restrict__ fcW,  const float* __restrict__ fcb,
    float*       __restrict__ out,
    ull* kx)   // (NB, KXS): per batch, 2 parities x 4 slice keys in one line
{
    const int tid  = threadIdx.x;
    const int lane = tid & 63;
    const int wvi  = tid >> 6;           // wave 0..7
    const int bx   = blockIdx.x;
    const int b    = bx >> 2;            // batch
    const int q    = bx & 3;             // vocab slice

    __shared__ __align__(16) float s_w[G4 * WST];   // 49.7 KB enc/dec weights
    __shared__ __align__(16) float s_x[112];        // x|h (enc: x[0..63] h@64; dec: x[0..31] h@32)
    __shared__ float s_g[G4];
    __shared__ ull   s_red[8];
    __shared__ int   s_tok;

    // ---- zero out[:, 0, :] (wave-contiguous float4) ----
    for (int idx = bx * NTHR + tid; idx < NB * (DE_VSZ / 4); idx += NBLK * NTHR) {
        const int bb = idx / (DE_VSZ / 4);
        const int qq = idx - bb * (DE_VSZ / 4);
        *(float4*)(out + (size_t)bb * OUT_B + (size_t)qq * 4) = make_float4(0.f, 0.f, 0.f, 0.f);
    }

    // ---- stage encoder weights: row r = eWih[r][0..63] | eWhh[r][0..31] ----
    for (int idx = tid; idx < G4 * 96; idx += NTHR) {
        const int row = idx / 96, k = idx - row * 96;
        s_w[row * WST + k] = (k < EMB_E) ? eWih[row * EMB_E + k]
                                         : eWhh[row * HID + (k - EMB_E)];
    }
    float ebs = 0.f, dbs = 0.f;
    if (tid < G4) { ebs = ebih[tid] + ebhh[tid]; dbs = dbih[tid] + dbhh[tid]; }
    float creg = 0.f;                      // cell state lives in tid<32 registers
    if (tid < HID) s_x[64 + tid] = 0.f;    // encoder h at s_x[64..95]
    if (tid == 0)  s_tok = de_batch[b * S_DE + 0];

    // ---- fc: row biases to registers (weights streamed from L2 per step) ----
    float fbs[NRPT];
    #pragma unroll
    for (int k = 0; k < NRPT; ++k) {
        const int lr = tid + k * NTHR;
        fbs[k] = (lr < SLR) ? fcb[q * SLR + lr] : 0.f;
    }
    __syncthreads();

    // ---- encoder for batch b (redundant x4, deterministic) ----
    const int len = en_lens[b];            // monotone mask == stop at len
    for (int t = 0; t < len; ++t) {
        const int etok = en_batch[b * S_EN + t];
        if (tid < 16)
            *(float4*)&s_x[tid * 4] = *(const float4*)&en_emb[(size_t)etok * EMB_E + tid * 4];
        __syncthreads();
        if (tid < G4) {
            float a = ebs;
            const float* wrow = &s_w[tid * WST];
            #pragma unroll
            for (int k = 0; k < 96; ++k) a = fmaf(s_x[k], wrow[k], a);
            s_g[tid] = a;
        }
        __syncthreads();
        if (tid < HID) {
            const float i  = sigmoidf_(s_g[tid]);
            const float f  = sigmoidf_(s_g[HID + tid]);
            const float gg = tanhf(s_g[2 * HID + tid]);
            const float o  = sigmoidf_(s_g[3 * HID + tid]);
            creg = f * creg + i * gg;
            s_x[64 + tid] = o * tanhf(creg);
        }
        __syncthreads();
    }

    // ---- handoff: h -> s_x[32..63]; restage decoder weights ----
    if (tid < HID) s_x[32 + tid] = s_x[64 + tid];   // same-thread copy, no race
    for (int idx = tid; idx < G4 * 64; idx += NTHR) {
        const int row = idx >> 6, k = idx & 63;
        s_w[row * WST + k] = (k < HID) ? dWih[row * HID + k]
                                       : dWhh[row * HID + (k - HID)];
    }
    __syncthreads();

    // ---- decoder: 49 steps ----
    for (int s = 1; s < S_DE; ++s) {
        // (a) x = de_emb[tok]
        {
            const int tok = s_tok;
            if (tid < 8)
                *(float4*)&s_x[tid * 4] = *(const float4*)&de_emb[(size_t)tok * EMB_D + tid * 4];
        }
        __syncthreads();

        // (b) gates: 128 threads, one gate each, conflict-free LDS (stride 97)
        if (tid < G4) {
            float a = dbs;
            const float* wrow = &s_w[tid * WST];
            #pragma unroll
            for (int k = 0; k < 64; ++k) a = fmaf(s_x[k], wrow[k], a);
            s_g[tid] = a;
        }
        __syncthreads();

        // (c) activations + state (cell state stays in tid<32 registers)
        if (tid < HID) {
            const float i  = sigmoidf_(s_g[tid]);
            const float f  = sigmoidf_(s_g[HID + tid]);
            const float gg = tanhf(s_g[2 * HID + tid]);
            const float o  = sigmoidf_(s_g[3 * HID + tid]);
            creg = f * creg + i * gg;
            s_x[32 + tid] = o * tanhf(creg);
        }
        __syncthreads();

        // (d) fc slice: ~10 rows/thread streamed from L2, h broadcast from LDS;
        //     lane-consecutive rows -> coalesced 256B wave stores; local argmax.
        float best = -FLT_MAX; int bestr = 0x7FFF;
        float* od = out + (size_t)b * OUT_B + (size_t)s * DE_VSZ;
        #pragma unroll
        for (int k = 0; k < NRPT; ++k) {
            const int  lr    = tid + k * NTHR;
            const bool valid = (lr < SLR);
            const int  r     = q * SLR + lr;
            const float4* w4p = (const float4*)&fcW[(size_t)(valid ? r : 0) * HID];
            float a = fbs[k];
            #pragma unroll
            for (int kc = 0; kc < 8; ++kc) {
                const float4 w4 = w4p[kc];
                const float4 h4 = *(const float4*)&s_x[32 + kc * 4];
                a = fmaf(w4.x, h4.x, a);
                a = fmaf(w4.y, h4.y, a);
                a = fmaf(w4.z, h4.z, a);
                a = fmaf(w4.w, h4.w, a);
            }
            if (valid) {
                od[r] = a;
                if (a > best) { best = a; bestr = r; }  // ascending rows -> first max
            }
        }
        if (s == S_DE - 1) break;   // final step: logits stored, no token needed

        // block argmax key: 64-lane shfl reduce, then 8 waves via LDS
        ull wkey = ((ull)ordf_(best) << 15) | (unsigned)((~bestr) & 0x7FFF);
        #pragma unroll
        for (int off = 1; off < 64; off <<= 1) {
            const ull ok = __shfl_xor(wkey, off);
            if (ok > wkey) wkey = ok;
        }
        if (lane == 0) s_red[wvi] = wkey;
        __syncthreads();

        const int par = s & 1;
        if (tid == 0) {
            ull m = s_red[0];
            #pragma unroll
            for (int w = 1; w < 8; ++w) if (s_red[w] > m) m = s_red[w];
            // publish via RMW-exchange: executes at the device coherence point
            (void)__hip_atomic_exchange(&kx[(size_t)b * KXS + par * 4 + q],
                                        ((ull)s << 47) | m,
                                        __ATOMIC_RELAXED, __HIP_MEMORY_SCOPE_AGENT);
        }

        // (e) poll the 4 sibling keys with RMW reads (fetch_add 0 -> coherent)
        ull kw = 0;
        int iter = 0;
        for (;;) {
            int ok = 1;
            if (wvi == 0 && lane < NSLB) {
                kw = __hip_atomic_fetch_add(&kx[(size_t)b * KXS + par * 4 + lane],
                                            0ull, __ATOMIC_RELAXED, __HIP_MEMORY_SCOPE_AGENT);
                ok = ((int)(kw >> 47) == s);
            }
            if (__syncthreads_and(ok)) break;
            if (++iter > POLL_CAP) break;   // safety: never hang the queue
            __builtin_amdgcn_s_sleep(8);
        }
        if (wvi == 0 && lane < NSLB) {
            ull m = kw;
            { const ull o1 = __shfl_xor(m, 1); if (o1 > m) m = o1; }
            { const ull o2 = __shfl_xor(m, 2); if (o2 > m) m = o2; }
            if (lane == 0) s_tok = (int)((~(unsigned)m) & 0x7FFF);
        }
        __syncthreads();
    }
}

extern "C" void kernel_launch(void* const* d_in, const int* in_sizes, int n_in,
                              void* d_out, int out_size, void* d_ws, size_t ws_size,
                              hipStream_t stream) {
    (void)in_sizes; (void)n_in; (void)out_size; (void)ws_size;
    const int*   en_batch = (const int*)  d_in[0];
    const int*   en_lens  = (const int*)  d_in[1];
    const int*   de_batch = (const int*)  d_in[2];
    const float* en_emb   = (const float*)d_in[3];
    const float* eWih     = (const float*)d_in[4];
    const float* eWhh     = (const float*)d_in[5];
    const float* ebih     = (const float*)d_in[6];
    const float* ebhh     = (const float*)d_in[7];
    const float* de_emb   = (const float*)d_in[8];
    const float* dWih     = (const float*)d_in[9];
    const float* dWhh     = (const float*)d_in[10];
    const float* dbih     = (const float*)d_in[11];
    const float* dbhh     = (const float*)d_in[12];
    const float* fcW      = (const float*)d_in[13];
    const float* fcb      = (const float*)d_in[14];
    float* out = (float*)d_out;

    ull* kx = (ull*)d_ws;                           // 64 * 16 * 8 = 8 KB
    hipMemsetAsync(d_ws, 0, 8192, stream);          // tag 0 != any step s>=1

    seq2seq_rmw4<<<NBLK, NTHR, 0, stream>>>(
        en_batch, en_lens, de_batch, en_emb, eWih, eWhh, ebih, ebhh,
        de_emb, dWih, dWhh, dbih, dbhh, fcW, fcb, out, kx);
}

// Round 7
// 995.350 us; speedup vs baseline: 3.9398x; 1.5087x over previous
//
#include <hip/hip_runtime.h>
#include <math.h>
#include <float.h>

#define NB     64      // batch
#define S_EN   50
#define S_DE   50
#define EMB_E  64
#define EMB_D  32
#define HID    32
#define G4     128     // 4*H
#define DE_VSZ 19000
#define OUT_B  (S_DE * DE_VSZ)

#define NSLB   4       // vocab slices per batch
#define SLR    4750    // rows per slice (4*4750 = 19000 exactly)
#define NBLK   (NB * NSLB)  // 256 blocks = CU count -> co-residency by capacity
#define NTHR   512     // 8 waves
#define NRPT   10      // fc rows per thread (ceil 4750/512)
#define WST    97      // LDS weight row stride: (97*t+k)%32=(t+k)%32 -> conflict-free
#define KXS    16      // kv u64-stride per batch (128 B: one line per batch)
#define POLL_CAP 200000 // bounded poll: failure -> terminating wrong answer

typedef unsigned long long ull;
typedef float floatx4 __attribute__((ext_vector_type(4)));   // nontemporal-legal

__device__ __forceinline__ float sigmoidf_(float x) { return 1.0f / (1.0f + expf(-x)); }

// monotone float->uint: a<b <=> ordf(a)<ordf(b)
__device__ __forceinline__ unsigned ordf_(float f) {
    unsigned u = __float_as_uint(f);
    return (u & 0x80000000u) ? ~u : (u | 0x80000000u);
}

// Grid: 256 blocks = 64 batches x 4 vocab slices; batches fully independent.
// Block (b,q) redundantly runs batch b's LSTM (bitwise identical across the
// 4 siblings) and owns fc rows [q*4750,(q+1)*4750), streamed from L2 each
// step. Rendezvous: 4-way per-batch exchange via atomic RMWs only (exchange
// to publish, fetch_add(0) to poll) -- executes at the device coherence
// point, so no fences / no L2-eviction-timing dependence.
// Changes vs rmw4 (passing, 1300us):
//  (1) NON-TEMPORAL out stores: stop evicting fc_W from each XCD L2
//      (round-5 FETCH showed full fc_W refetched per step per XCD).
//  (2) publish argmax key BEFORE draining out stores (stores overlap poll).
//  (3) wave0-only spin poll, no per-iteration block barrier, s_sleep(1).
__global__ __launch_bounds__(NTHR, 2) void seq2seq_rmw5(
    const int*   __restrict__ en_batch, const int* __restrict__ en_lens,
    const int*   __restrict__ de_batch,
    const float* __restrict__ en_emb,
    const float* __restrict__ eWih, const float* __restrict__ eWhh,
    const float* __restrict__ ebih, const float* __restrict__ ebhh,
    const float* __restrict__ de_emb,
    const float* __restrict__ dWih, const float* __restrict__ dWhh,
    const float* __restrict__ dbih, const float* __restrict__ dbhh,
    const float* __restrict__ fcW,  const float* __restrict__ fcb,
    float*       __restrict__ out,
    ull* kx)   // (NB, KXS): per batch, 2 parities x 4 slice keys in one line
{
    const int tid  = threadIdx.x;
    const int lane = tid & 63;
    const int wvi  = tid >> 6;           // wave 0..7
    const int bx   = blockIdx.x;
    const int b    = bx >> 2;            // batch
    const int q    = bx & 3;             // vocab slice

    __shared__ __align__(16) float s_w[G4 * WST];   // 49.7 KB enc/dec weights
    __shared__ __align__(16) float s_x[112];        // x|h (enc: x[0..63] h@64; dec: x[0..31] h@32)
    __shared__ float s_g[G4];
    __shared__ ull   s_red[8];
    __shared__ int   s_tok;

    // ---- zero out[:, 0, :] (wave-contiguous, non-temporal) ----
    for (int idx = bx * NTHR + tid; idx < NB * (DE_VSZ / 4); idx += NBLK * NTHR) {
        const int bb = idx / (DE_VSZ / 4);
        const int qq = idx - bb * (DE_VSZ / 4);
        const floatx4 z = {0.f, 0.f, 0.f, 0.f};
        __builtin_nontemporal_store(z,
            (floatx4*)(out + (size_t)bb * OUT_B + (size_t)qq * 4));
    }

    // ---- stage encoder weights: row r = eWih[r][0..63] | eWhh[r][0..31] ----
    for (int idx = tid; idx < G4 * 96; idx += NTHR) {
        const int row = idx / 96, k = idx - row * 96;
        s_w[row * WST + k] = (k < EMB_E) ? eWih[row * EMB_E + k]
                                         : eWhh[row * HID + (k - EMB_E)];
    }
    float ebs = 0.f, dbs = 0.f;
    if (tid < G4) { ebs = ebih[tid] + ebhh[tid]; dbs = dbih[tid] + dbhh[tid]; }
    float creg = 0.f;                      // cell state lives in tid<32 registers
    if (tid < HID) s_x[64 + tid] = 0.f;    // encoder h at s_x[64..95]
    if (tid == 0)  s_tok = de_batch[b * S_DE + 0];

    // ---- fc: row biases to registers (weights streamed from L2 per step) ----
    float fbs[NRPT];
    #pragma unroll
    for (int k = 0; k < NRPT; ++k) {
        const int lr = tid + k * NTHR;
        fbs[k] = (lr < SLR) ? fcb[q * SLR + lr] : 0.f;
    }
    __syncthreads();

    // ---- encoder for batch b (redundant x4, deterministic) ----
    const int len = en_lens[b];            // monotone mask == stop at len
    for (int t = 0; t < len; ++t) {
        const int etok = en_batch[b * S_EN + t];
        if (tid < 16)
            *(float4*)&s_x[tid * 4] = *(const float4*)&en_emb[(size_t)etok * EMB_E + tid * 4];
        __syncthreads();
        if (tid < G4) {
            float a = ebs;
            const float* wrow = &s_w[tid * WST];
            #pragma unroll
            for (int k = 0; k < 96; ++k) a = fmaf(s_x[k], wrow[k], a);
            s_g[tid] = a;
        }
        __syncthreads();
        if (tid < HID) {
            const float i  = sigmoidf_(s_g[tid]);
            const float f  = sigmoidf_(s_g[HID + tid]);
            const float gg = tanhf(s_g[2 * HID + tid]);
            const float o  = sigmoidf_(s_g[3 * HID + tid]);
            creg = f * creg + i * gg;
            s_x[64 + tid] = o * tanhf(creg);
        }
        __syncthreads();
    }

    // ---- handoff: h -> s_x[32..63]; restage decoder weights ----
    if (tid < HID) s_x[32 + tid] = s_x[64 + tid];   // same-thread copy, no race
    for (int idx = tid; idx < G4 * 64; idx += NTHR) {
        const int row = idx >> 6, k = idx & 63;
        s_w[row * WST + k] = (k < HID) ? dWih[row * HID + k]
                                       : dWhh[row * HID + (k - HID)];
    }
    __syncthreads();

    // ---- decoder: 49 steps ----
    for (int s = 1; s < S_DE; ++s) {
        // (a) x = de_emb[tok]
        {
            const int tok = s_tok;
            if (tid < 8)
                *(float4*)&s_x[tid * 4] = *(const float4*)&de_emb[(size_t)tok * EMB_D + tid * 4];
        }
        __syncthreads();

        // (b) gates: 128 threads, one gate each, conflict-free LDS (stride 97)
        if (tid < G4) {
            float a = dbs;
            const float* wrow = &s_w[tid * WST];
            #pragma unroll
            for (int k = 0; k < 64; ++k) a = fmaf(s_x[k], wrow[k], a);
            s_g[tid] = a;
        }
        __syncthreads();

        // (c) activations + state (cell state stays in tid<32 registers)
        if (tid < HID) {
            const float i  = sigmoidf_(s_g[tid]);
            const float f  = sigmoidf_(s_g[HID + tid]);
            const float gg = tanhf(s_g[2 * HID + tid]);
            const float o  = sigmoidf_(s_g[3 * HID + tid]);
            creg = f * creg + i * gg;
            s_x[32 + tid] = o * tanhf(creg);
        }
        __syncthreads();

        // (d1) fc slice: ~10 rows/thread from L2, h broadcast from LDS;
        //      logits kept in registers, local argmax on the fly.
        float accv[NRPT];
        float best = -FLT_MAX; int bestr = 0x7FFF;
        #pragma unroll
        for (int k = 0; k < NRPT; ++k) {
            const int  lr    = tid + k * NTHR;
            const bool valid = (lr < SLR);
            const int  r     = q * SLR + lr;
            const float4* w4p = (const float4*)&fcW[(size_t)(valid ? r : 0) * HID];
            float a = fbs[k];
            #pragma unroll
            for (int kc = 0; kc < 8; ++kc) {
                const float4 w4 = w4p[kc];
                const float4 h4 = *(const float4*)&s_x[32 + kc * 4];
                a = fmaf(w4.x, h4.x, a);
                a = fmaf(w4.y, h4.y, a);
                a = fmaf(w4.z, h4.z, a);
                a = fmaf(w4.w, h4.w, a);
            }
            accv[k] = a;
            if (valid && a > best) { best = a; bestr = r; }  // ascending -> first max
        }

        const int par = s & 1;
        // (d2) publish argmax key FIRST (stores overlap the siblings' polls)
        if (s < S_DE - 1) {
            ull wkey = ((ull)ordf_(best) << 15) | (unsigned)((~bestr) & 0x7FFF);
            #pragma unroll
            for (int off = 1; off < 64; off <<= 1) {
                const ull ok = __shfl_xor(wkey, off);
                if (ok > wkey) wkey = ok;
            }
            if (lane == 0) s_red[wvi] = wkey;
            __syncthreads();
            if (tid == 0) {
                ull m = s_red[0];
                #pragma unroll
                for (int w = 1; w < 8; ++w) if (s_red[w] > m) m = s_red[w];
                // RMW-exchange: executes at the device coherence point
                (void)__hip_atomic_exchange(&kx[(size_t)b * KXS + par * 4 + q],
                                            ((ull)s << 47) | m,
                                            __ATOMIC_RELAXED, __HIP_MEMORY_SCOPE_AGENT);
            }
        }

        // (d3) non-temporal logit stores (don't evict fc_W from L2)
        {
            float* od = out + (size_t)b * OUT_B + (size_t)s * DE_VSZ + (size_t)q * SLR;
            #pragma unroll
            for (int k = 0; k < NRPT; ++k) {
                const int lr = tid + k * NTHR;
                if (lr < SLR) __builtin_nontemporal_store(accv[k], &od[lr]);
            }
        }
        if (s == S_DE - 1) break;   // final step: logits stored, no token needed

        // (e) wave0-only spin poll (no per-iter block barrier); others wait at
        //     the single barrier below. POLL_CAP keeps any failure terminating.
        if (wvi == 0) {
            ull kw = 0;
            int ok = (lane >= NSLB);
            for (int iter = 0; iter < POLL_CAP; ++iter) {
                if (lane < NSLB) {
                    kw = __hip_atomic_fetch_add(&kx[(size_t)b * KXS + par * 4 + lane],
                                                0ull, __ATOMIC_RELAXED, __HIP_MEMORY_SCOPE_AGENT);
                    ok = ((int)(kw >> 47) == s);
                }
                if (__all(ok)) break;
                __builtin_amdgcn_s_sleep(1);
            }
            ull m = (lane < NSLB) ? kw : 0ull;
            { const ull o1 = __shfl_xor(m, 1); if (o1 > m) m = o1; }
            { const ull o2 = __shfl_xor(m, 2); if (o2 > m) m = o2; }
            if (lane == 0) s_tok = (int)((~(unsigned)m) & 0x7FFF);
        }
        __syncthreads();
    }
}

extern "C" void kernel_launch(void* const* d_in, const int* in_sizes, int n_in,
                              void* d_out, int out_size, void* d_ws, size_t ws_size,
                              hipStream_t stream) {
    (void)in_sizes; (void)n_in; (void)out_size; (void)ws_size;
    const int*   en_batch = (const int*)  d_in[0];
    const int*   en_lens  = (const int*)  d_in[1];
    const int*   de_batch = (const int*)  d_in[2];
    const float* en_emb   = (const float*)d_in[3];
    const float* eWih     = (const float*)d_in[4];
    const float* eWhh     = (const float*)d_in[5];
    const float* ebih     = (const float*)d_in[6];
    const float* ebhh     = (const float*)d_in[7];
    const float* de_emb   = (const float*)d_in[8];
    const float* dWih     = (const float*)d_in[9];
    const float* dWhh     = (const float*)d_in[10];
    const float* dbih     = (const float*)d_in[11];
    const float* dbhh     = (const float*)d_in[12];
    const float* fcW      = (const float*)d_in[13];
    const float* fcb      = (const float*)d_in[14];
    float* out = (float*)d_out;

    ull* kx = (ull*)d_ws;                           // 64 * 16 * 8 = 8 KB
    (void)hipMemsetAsync(d_ws, 0, 8192, stream);    // tag 0 != any step s>=1

    seq2seq_rmw5<<<NBLK, NTHR, 0, stream>>>(
        en_batch, en_lens, de_batch, en_emb, eWih, eWhh, ebih, ebhh,
        de_emb, dWih, dWhh, dbih, dbhh, fcW, fcb, out, kx);
}